// Round 3
// baseline (112.083 us; speedup 1.0000x reference)
//
#include <hip/hip_runtime.h>
#include <math.h>

// Weighted Hausdorff Distance — B=8, H=W=256 (N=65536 pixels), G=128.
// Compute-bound: 67.1M pair computations. Layout: 4-lane groups share a
// pixel; each lane owns a 32-g chunk with register accumulators.

#define HH 256
#define WW 256
#define BB 8
#define GG 128
#define NPIX (HH * WW)
#define BPB 128                       // blocks per batch item
#define MAXD 362.03867196751236f      // sqrt(256^2 + 256^2)

__device__ __forceinline__ float wave_sum(float v) {
    v += __shfl_xor(v, 1);  v += __shfl_xor(v, 2);  v += __shfl_xor(v, 4);
    v += __shfl_xor(v, 8);  v += __shfl_xor(v, 16); v += __shfl_xor(v, 32);
    return v;
}

// Partials layout in d_ws (floats):
//   rows 0..127 : per-g sums of (wd+1e-6)^-9        [g*1024 + b*BPB + blk]
//   row 128     : per-block sum of p*min_d          [128*1024 + b*BPB + blk]
//   row 129     : per-block sum of p                [129*1024 + b*BPB + blk]
// Total 130*1024*4 = 532480 bytes.

__global__ __launch_bounds__(256) void whd_main(const float* __restrict__ prob,
                                                const float* __restrict__ gt,
                                                const float* __restrict__ osz,
                                                float* __restrict__ part) {
    const int bid  = blockIdx.x;
    const int b    = bid >> 7;            // / BPB
    const int blk  = bid & (BPB - 1);
    const int tid  = threadIdx.x;
    const int lane = tid & 63;
    const int wv   = tid >> 6;
    const int chunk = tid & 3;            // which 32-g chunk this lane owns
    const int pt    = tid >> 2;           // pixel-thread id, 0..63

    __shared__ float2 ys[132];            // padded: index g + (g>>5)
    __shared__ float  redS[4][132];
    __shared__ float2 redT[4];

    const float nh = osz[b * 2]     * (1.0f / (float)HH);
    const float nw = osz[b * 2 + 1] * (1.0f / (float)WW);

    if (tid < GG) {
        float gr = gt[(b * GG + tid) * 2];
        float gc = gt[(b * GG + tid) * 2 + 1];
        ys[tid + (tid >> 5)] = make_float2(gr * nh, gc * nw);
    }
    __syncthreads();

    const float* pb = prob + b * NPIX;

    float acc[32];
#pragma unroll
    for (int j = 0; j < 32; j++) acc[j] = 0.0f;
    float t1acc = 0.0f, pacc = 0.0f;

    const int ysbase = chunk * 33;
    const int pix0   = blk * 512 + pt;

#pragma unroll 1
    for (int i = 0; i < 4; i++) {
        const int pixA = pix0 + i * 128;
        const int pixB = pixA + 64;
        const float pA = pb[pixA];
        const float pB = pb[pixB];
        const float xrA = (float)(pixA >> 8) * nh;
        const float xcA = (float)(pixA & 255) * nw;
        const float xrB = (float)(pixB >> 8) * nh;
        const float xcB = (float)(pixB & 255) * nw;
        // (1-p)*MAXD + 1e-6  (the wd + 1e-6 epsilon folded in)
        const float bA = (1.0f - pA) * MAXD + 1e-6f;
        const float bB = (1.0f - pB) * MAXD + 1e-6f;
        float mA = 1e30f, mB = 1e30f;

#pragma unroll
        for (int j = 0; j < 32; j++) {
            const float2 y = ys[ysbase + j];
            float dxA = xrA - y.x, dyA = xcA - y.y;
            float dA  = __builtin_amdgcn_sqrtf(fmaf(dxA, dxA, dyA * dyA));
            float dxB = xrB - y.x, dyB = xcB - y.y;
            float dB  = __builtin_amdgcn_sqrtf(fmaf(dxB, dxB, dyB * dyB));
            mA = fminf(mA, dA);
            mB = fminf(mB, dB);
            float tA = fmaf(pA, dA, bA);     // wd + 1e-6
            float tB = fmaf(pB, dB, bB);
            float uA = tA * tA; uA = uA * uA; uA = uA * uA; uA = uA * tA; // t^9
            float uB = tB * tB; uB = uB * uB; uB = uB * uB; uB = uB * tB;
            acc[j] += __builtin_amdgcn_rcpf(uA) + __builtin_amdgcn_rcpf(uB);
        }
        // min over all 128 g: combine the 4 chunk-lanes sharing this pixel
        mA = fminf(mA, __shfl_xor(mA, 1)); mA = fminf(mA, __shfl_xor(mA, 2));
        mB = fminf(mB, __shfl_xor(mB, 1)); mB = fminf(mB, __shfl_xor(mB, 2));
        t1acc = fmaf(pA, mA, t1acc);
        t1acc = fmaf(pB, mB, t1acc);
        pacc += pA + pB;
    }

    // per-g sums: reduce across the 16 same-chunk lanes of this wave
#pragma unroll
    for (int j = 0; j < 32; j++) {
        float v = acc[j];
        v += __shfl_xor(v, 4);  v += __shfl_xor(v, 8);
        v += __shfl_xor(v, 16); v += __shfl_xor(v, 32);
        acc[j] = v;
    }
    t1acc = wave_sum(t1acc);   // each pixel counted 4x (once per chunk lane)
    pacc  = wave_sum(pacc);

    if (lane < 4) {
#pragma unroll
        for (int j = 0; j < 32; j++) redS[wv][lane * 33 + j] = acc[j];
    }
    if (lane == 0) redT[wv] = make_float2(t1acc, pacc);
    __syncthreads();

    if (tid < GG) {
        const int idx = (tid >> 5) * 33 + (tid & 31);   // g == tid
        part[tid * 1024 + bid] =
            redS[0][idx] + redS[1][idx] + redS[2][idx] + redS[3][idx];
    } else if (tid == GG) {
        float t1 = redT[0].x + redT[1].x + redT[2].x + redT[3].x;
        float pp = redT[0].y + redT[1].y + redT[2].y + redT[3].y;
        part[128 * 1024 + bid] = t1 * 0.25f;   // undo 4x pixel multiplicity
        part[129 * 1024 + bid] = pp * 0.25f;
    }
}

__global__ __launch_bounds__(256) void whd_final(const float* __restrict__ part,
                                                 float* __restrict__ out) {
    const int tid  = threadIdx.x;
    const int lane = tid & 63;
    const int wv   = tid >> 6;

    // term2: minn[g] = (mean_n (wd+1e-6)^-9)^(1/-9); sum over all (b,g)
    float a2 = 0.0f;
    for (int pair = tid; pair < BB * GG; pair += 256) {
        const int b = pair >> 7;
        const int g = pair & 127;
        const float* pp = part + g * 1024 + b * BPB;
        float s = 0.0f;
#pragma unroll 4
        for (int k = 0; k < BPB; k++) s += pp[k];
        float mean = s * (1.0f / (float)NPIX);
        a2 += powf(mean, -0.111111111111111111f);   // 1 / P_EXP
    }

    // term1: sum(p*min_d) / (sum(p) + 1e-6), one per b
    float a1 = 0.0f;
    if (tid < BB) {
        const float* p1 = part + 128 * 1024 + tid * BPB;
        const float* p2 = part + 129 * 1024 + tid * BPB;
        float t1 = 0.0f, sp = 0.0f;
#pragma unroll 4
        for (int k = 0; k < BPB; k++) { t1 += p1[k]; sp += p2[k]; }
        a1 = t1 / (sp + 1e-6f);
    }

    a2 = wave_sum(a2);
    a1 = wave_sum(a1);

    __shared__ float r1[4], r2[4];
    if (lane == 0) { r1[wv] = a1; r2[wv] = a2; }
    __syncthreads();
    if (tid == 0) {
        float s1 = r1[0] + r1[1] + r1[2] + r1[3];
        float s2 = r2[0] + r2[1] + r2[2] + r2[3];
        out[0] = s1 * (1.0f / (float)BB) + s2 * (1.0f / (float)(BB * GG));
    }
}

extern "C" void kernel_launch(void* const* d_in, const int* in_sizes, int n_in,
                              void* d_out, int out_size, void* d_ws, size_t ws_size,
                              hipStream_t stream) {
    const float* prob = (const float*)d_in[0];   // [B, H, W]
    const float* gt   = (const float*)d_in[1];   // [B, G, 2]
    const float* osz  = (const float*)d_in[2];   // [B, 2]
    float* out  = (float*)d_out;                 // [1]
    float* part = (float*)d_ws;                  // 130*1024 floats = 532 KB

    whd_main<<<BB * BPB, 256, 0, stream>>>(prob, gt, osz, part);
    whd_final<<<1, 256, 0, stream>>>(part, out);
}

// Round 4
// 93.751 us; speedup vs baseline: 1.1956x; 1.1956x over previous
//
#include <hip/hip_runtime.h>
#include <math.h>

// Weighted Hausdorff Distance — B=8, H=W=256 (N=65536 pixels), G=128.
// Compute-bound main (67.1M pair computations): 4-lane groups share a pixel,
// each lane owns a 32-g chunk in register accumulators.
// Partials layout: part[row][132], row = b*128 + blk (1024 rows).
//   cols 0..127 : per-g block sums of (wd+1e-6)^-9
//   col  128    : block sum of p*min_d
//   col  129    : block sum of p
// 1024*132*4 = 540,672 bytes of d_ws.

#define HH 256
#define WW 256
#define BB 8
#define GG 128
#define NPIX (HH * WW)
#define BPB 128                       // blocks per batch item
#define ROWW 132                      // padded row width (33 float4s)
#define MAXD 362.03867196751236f      // sqrt(256^2 + 256^2)

__device__ __forceinline__ float wave_sum(float v) {
    v += __shfl_xor(v, 1);  v += __shfl_xor(v, 2);  v += __shfl_xor(v, 4);
    v += __shfl_xor(v, 8);  v += __shfl_xor(v, 16); v += __shfl_xor(v, 32);
    return v;
}

__global__ __launch_bounds__(256) void whd_main(const float* __restrict__ prob,
                                                const float* __restrict__ gt,
                                                const float* __restrict__ osz,
                                                float* __restrict__ part) {
    const int bid  = blockIdx.x;
    const int b    = bid >> 7;            // / BPB
    const int blk  = bid & (BPB - 1);
    const int tid  = threadIdx.x;
    const int lane = tid & 63;
    const int wv   = tid >> 6;
    const int chunk = tid & 3;            // which 32-g chunk this lane owns
    const int pt    = tid >> 2;           // pixel-thread id, 0..63

    __shared__ float2 ys[132];            // padded: index g + (g>>5)
    __shared__ float  redS[4][132];
    __shared__ float2 redT[4];

    const float nh = osz[b * 2]     * (1.0f / (float)HH);
    const float nw = osz[b * 2 + 1] * (1.0f / (float)WW);

    if (tid < GG) {
        float gr = gt[(b * GG + tid) * 2];
        float gc = gt[(b * GG + tid) * 2 + 1];
        ys[tid + (tid >> 5)] = make_float2(gr * nh, gc * nw);
    }
    __syncthreads();

    const float* pb = prob + b * NPIX;

    float acc[32];
#pragma unroll
    for (int j = 0; j < 32; j++) acc[j] = 0.0f;
    float t1acc = 0.0f, pacc = 0.0f;

    const int ysbase = chunk * 33;
    const int pix0   = blk * 512 + pt;

#pragma unroll 1
    for (int i = 0; i < 4; i++) {
        const int pixA = pix0 + i * 128;
        const int pixB = pixA + 64;
        const float pA = pb[pixA];
        const float pB = pb[pixB];
        const float xrA = (float)(pixA >> 8) * nh;
        const float xcA = (float)(pixA & 255) * nw;
        const float xrB = (float)(pixB >> 8) * nh;
        const float xcB = (float)(pixB & 255) * nw;
        // (1-p)*MAXD + 1e-6  (the wd + 1e-6 epsilon folded in)
        const float bA = (1.0f - pA) * MAXD + 1e-6f;
        const float bB = (1.0f - pB) * MAXD + 1e-6f;
        float mA = 1e30f, mB = 1e30f;

#pragma unroll
        for (int j = 0; j < 32; j++) {
            const float2 y = ys[ysbase + j];
            float dxA = xrA - y.x, dyA = xcA - y.y;
            float dA  = __builtin_amdgcn_sqrtf(fmaf(dxA, dxA, dyA * dyA));
            float dxB = xrB - y.x, dyB = xcB - y.y;
            float dB  = __builtin_amdgcn_sqrtf(fmaf(dxB, dxB, dyB * dyB));
            mA = fminf(mA, dA);
            mB = fminf(mB, dB);
            float tA = fmaf(pA, dA, bA);     // wd + 1e-6
            float tB = fmaf(pB, dB, bB);
            float uA = tA * tA; uA = uA * uA; uA = uA * uA; uA = uA * tA; // t^9
            float uB = tB * tB; uB = uB * uB; uB = uB * uB; uB = uB * tB;
            acc[j] += __builtin_amdgcn_rcpf(uA) + __builtin_amdgcn_rcpf(uB);
        }
        // min over all 128 g: combine the 4 chunk-lanes sharing this pixel
        mA = fminf(mA, __shfl_xor(mA, 1)); mA = fminf(mA, __shfl_xor(mA, 2));
        mB = fminf(mB, __shfl_xor(mB, 1)); mB = fminf(mB, __shfl_xor(mB, 2));
        t1acc = fmaf(pA, mA, t1acc);
        t1acc = fmaf(pB, mB, t1acc);
        pacc += pA + pB;
    }

    // per-g sums: reduce across the 16 same-chunk lanes of this wave
#pragma unroll
    for (int j = 0; j < 32; j++) {
        float v = acc[j];
        v += __shfl_xor(v, 4);  v += __shfl_xor(v, 8);
        v += __shfl_xor(v, 16); v += __shfl_xor(v, 32);
        acc[j] = v;
    }
    t1acc = wave_sum(t1acc);   // each pixel counted 4x (once per chunk lane)
    pacc  = wave_sum(pacc);

    if (lane < 4) {
#pragma unroll
        for (int j = 0; j < 32; j++) redS[wv][lane * 33 + j] = acc[j];
    }
    if (lane == 0) redT[wv] = make_float2(t1acc, pacc);
    __syncthreads();

    // coalesced partials write: row `bid`, 128 consecutive floats + (t1,p)
    if (tid < GG) {
        const int idx = (tid >> 5) * 33 + (tid & 31);   // g == tid
        part[bid * ROWW + tid] =
            redS[0][idx] + redS[1][idx] + redS[2][idx] + redS[3][idx];
    } else if (tid == GG) {
        float t1 = redT[0].x + redT[1].x + redT[2].x + redT[3].x;
        float pp = redT[0].y + redT[1].y + redT[2].y + redT[3].y;
        part[bid * ROWW + 128] = t1 * 0.25f;   // undo 4x pixel multiplicity
        part[bid * ROWW + 129] = pp * 0.25f;
    }
}

__global__ __launch_bounds__(1024) void whd_final(const float* __restrict__ part,
                                                  float* __restrict__ out) {
    const int tid  = threadIdx.x;       // 0..1023, one (b,g) pair per thread
    const int lane = tid & 63;
    const int wv   = tid >> 6;          // 0..15
    const int b    = tid >> 7;
    const int g    = tid & 127;

    // term2: sum over this b's 128 blocks; lanes read consecutive g -> coalesced
    const float* base = part + (b * BPB) * ROWW + g;
    float s = 0.0f;
#pragma unroll 8
    for (int k = 0; k < BPB; k++) s += base[k * ROWW];
    float mean = s * (1.0f / (float)NPIX);
    float a2 = powf(mean, -0.111111111111111111f);   // 1 / P_EXP

    // term1 partials: thread tid reads row tid's (t1, p)
    const float2 tp = *(const float2*)(part + tid * ROWW + 128);

    float wa = wave_sum(a2);
    float wt = wave_sum(tp.x);   // rows of one b span exactly 2 waves
    float wp = wave_sum(tp.y);

    __shared__ float sA[16], sT[16], sP[16];
    if (lane == 0) { sA[wv] = wa; sT[wv] = wt; sP[wv] = wp; }
    __syncthreads();

    if (tid == 0) {
        float tot2 = 0.0f;
#pragma unroll
        for (int w = 0; w < 16; w++) tot2 += sA[w];
        float tot1 = 0.0f;
#pragma unroll
        for (int bb = 0; bb < BB; bb++) {
            float tb = sT[2 * bb] + sT[2 * bb + 1];
            float pb = sP[2 * bb] + sP[2 * bb + 1];
            tot1 += tb / (pb + 1e-6f);
        }
        out[0] = tot1 * (1.0f / (float)BB) + tot2 * (1.0f / (float)(BB * GG));
    }
}

extern "C" void kernel_launch(void* const* d_in, const int* in_sizes, int n_in,
                              void* d_out, int out_size, void* d_ws, size_t ws_size,
                              hipStream_t stream) {
    const float* prob = (const float*)d_in[0];   // [B, H, W]
    const float* gt   = (const float*)d_in[1];   // [B, G, 2]
    const float* osz  = (const float*)d_in[2];   // [B, 2]
    float* out  = (float*)d_out;                 // [1]
    float* part = (float*)d_ws;                  // 1024*132 floats = 540 KB

    whd_main<<<BB * BPB, 256, 0, stream>>>(prob, gt, osz, part);
    whd_final<<<1, 1024, 0, stream>>>(part, out);
}

// Round 8
// 92.835 us; speedup vs baseline: 1.2073x; 1.0099x over previous
//
#include <hip/hip_runtime.h>
#include <math.h>

// Weighted Hausdorff Distance — B=8, H=W=256 (N=65536 pixels), G=128.
// Main kernel: 8-lane groups share a pixel; each lane owns a 16-g chunk in
// register accumulators (acc[16] + 16 hoisted float2 ys -> low VGPR, 4 blocks/CU).
// Partials layout: part[row][132], row = b*128 + blk (1024 rows).
//   cols 0..127 : per-g block sums of (wd+1e-6)^-9
//   col  128    : block sum of p*min_d
//   col  129    : block sum of p
// 1024*132*4 = 540,672 bytes of d_ws.

#define HH 256
#define WW 256
#define BB 8
#define GG 128
#define NPIX (HH * WW)
#define BPB 128                       // blocks per batch item
#define ROWW 132                      // padded row width (33 float4s)
#define MAXD 362.03867196751236f      // sqrt(256^2 + 256^2)

__device__ __forceinline__ float wave_sum(float v) {
    v += __shfl_xor(v, 1);  v += __shfl_xor(v, 2);  v += __shfl_xor(v, 4);
    v += __shfl_xor(v, 8);  v += __shfl_xor(v, 16); v += __shfl_xor(v, 32);
    return v;
}

__global__ __launch_bounds__(256, 4) void whd_main(const float* __restrict__ prob,
                                                   const float* __restrict__ gt,
                                                   const float* __restrict__ osz,
                                                   float* __restrict__ part) {
    const int bid  = blockIdx.x;
    const int b    = bid >> 7;            // / BPB
    const int blk  = bid & (BPB - 1);
    const int tid  = threadIdx.x;
    const int lane = tid & 63;
    const int wv   = tid >> 6;
    const int chunk = tid & 7;            // which 16-g chunk this lane owns
    const int pt    = tid >> 3;           // pixel-slot id, 0..31

    __shared__ float2 ys[137];            // padded: index 17*(g>>4) + (g&15)
    __shared__ float  redS[4][137];
    __shared__ float2 redT[4];

    const float nh = osz[b * 2]     * (1.0f / (float)HH);
    const float nw = osz[b * 2 + 1] * (1.0f / (float)WW);

    if (tid < GG) {
        float gr = gt[(b * GG + tid) * 2];
        float gc = gt[(b * GG + tid) * 2 + 1];
        ys[tid + (tid >> 4)] = make_float2(gr * nh, gc * nw);
    }
    __syncthreads();

    const float* pb = prob + b * NPIX;

    float acc[16];
#pragma unroll
    for (int j = 0; j < 16; j++) acc[j] = 0.0f;
    float t1acc = 0.0f, pacc = 0.0f;

    const int ysbase = chunk * 17;
    const int pix0   = blk * 512 + pt;

#pragma unroll 1
    for (int i = 0; i < 8; i++) {
        const int pixA = pix0 + i * 64;
        const int pixB = pixA + 32;
        const float pA = pb[pixA];
        const float pB = pb[pixB];
        const float xrA = (float)(pixA >> 8) * nh;
        const float xcA = (float)(pixA & 255) * nw;
        const float xrB = (float)(pixB >> 8) * nh;
        const float xcB = (float)(pixB & 255) * nw;
        // (1-p)*MAXD + 1e-6  (the wd + 1e-6 epsilon folded in)
        const float bA = (1.0f - pA) * MAXD + 1e-6f;
        const float bB = (1.0f - pB) * MAXD + 1e-6f;
        float mA = 1e30f, mB = 1e30f;

#pragma unroll
        for (int j = 0; j < 16; j++) {
            const float2 y = ys[ysbase + j];
            float dxA = xrA - y.x, dyA = xcA - y.y;
            float dA  = __builtin_amdgcn_sqrtf(fmaf(dxA, dxA, dyA * dyA));
            float dxB = xrB - y.x, dyB = xcB - y.y;
            float dB  = __builtin_amdgcn_sqrtf(fmaf(dxB, dxB, dyB * dyB));
            mA = fminf(mA, dA);
            mB = fminf(mB, dB);
            float tA = fmaf(pA, dA, bA);     // wd + 1e-6
            float tB = fmaf(pB, dB, bB);
            float uA = tA * tA; uA = uA * uA; uA = uA * uA; uA = uA * tA; // t^9
            float uB = tB * tB; uB = uB * uB; uB = uB * uB; uB = uB * tB;
            acc[j] += __builtin_amdgcn_rcpf(uA) + __builtin_amdgcn_rcpf(uB);
        }
        // min over all 128 g: combine the 8 chunk-lanes sharing this pixel
        mA = fminf(mA, __shfl_xor(mA, 1)); mA = fminf(mA, __shfl_xor(mA, 2));
        mA = fminf(mA, __shfl_xor(mA, 4));
        mB = fminf(mB, __shfl_xor(mB, 1)); mB = fminf(mB, __shfl_xor(mB, 2));
        mB = fminf(mB, __shfl_xor(mB, 4));
        t1acc = fmaf(pA, mA, t1acc);
        t1acc = fmaf(pB, mB, t1acc);
        pacc += pA + pB;
    }

    // per-g sums: reduce across the 8 same-chunk lanes of this wave
#pragma unroll
    for (int j = 0; j < 16; j++) {
        float v = acc[j];
        v += __shfl_xor(v, 8);  v += __shfl_xor(v, 16); v += __shfl_xor(v, 32);
        acc[j] = v;
    }
    t1acc = wave_sum(t1acc);   // each pixel counted 8x (once per chunk lane)
    pacc  = wave_sum(pacc);

    if (lane < 8) {
#pragma unroll
        for (int j = 0; j < 16; j++) redS[wv][lane * 17 + j] = acc[j];
    }
    if (lane == 0) redT[wv] = make_float2(t1acc, pacc);
    __syncthreads();

    // coalesced partials write: row `bid`, 128 consecutive floats + (t1,p)
    if (tid < GG) {
        const int idx = (tid >> 4) * 17 + (tid & 15);   // g == tid
        part[bid * ROWW + tid] =
            redS[0][idx] + redS[1][idx] + redS[2][idx] + redS[3][idx];
    } else if (tid == GG) {
        float t1 = redT[0].x + redT[1].x + redT[2].x + redT[3].x;
        float pp = redT[0].y + redT[1].y + redT[2].y + redT[3].y;
        part[bid * ROWW + 128] = t1 * 0.125f;   // undo 8x pixel multiplicity
        part[bid * ROWW + 129] = pp * 0.125f;
    }
}

__global__ __launch_bounds__(1024) void whd_final(const float* __restrict__ part,
                                                  float* __restrict__ out) {
    const int tid  = threadIdx.x;       // 0..1023, one (b,g) pair per thread
    const int lane = tid & 63;
    const int wv   = tid >> 6;          // 0..15
    const int b    = tid >> 7;
    const int g    = tid & 127;

    // term2: sum over this b's 128 blocks; lanes read consecutive g -> coalesced
    const float* base = part + (b * BPB) * ROWW + g;
    float s = 0.0f;
#pragma unroll 8
    for (int k = 0; k < BPB; k++) s += base[k * ROWW];
    float mean = s * (1.0f / (float)NPIX);
    float a2 = powf(mean, -0.111111111111111111f);   // 1 / P_EXP

    // term1 partials: thread tid reads row tid's (t1, p)
    const float2 tp = *(const float2*)(part + tid * ROWW + 128);

    float wa = wave_sum(a2);
    float wt = wave_sum(tp.x);   // rows of one b span exactly 2 waves
    float wp = wave_sum(tp.y);

    __shared__ float sA[16], sT[16], sP[16];
    if (lane == 0) { sA[wv] = wa; sT[wv] = wt; sP[wv] = wp; }
    __syncthreads();

    if (tid == 0) {
        float tot2 = 0.0f;
#pragma unroll
        for (int w = 0; w < 16; w++) tot2 += sA[w];
        float tot1 = 0.0f;
#pragma unroll
        for (int bb = 0; bb < BB; bb++) {
            float tb = sT[2 * bb] + sT[2 * bb + 1];
            float pb = sP[2 * bb] + sP[2 * bb + 1];
            tot1 += tb / (pb + 1e-6f);
        }
        out[0] = tot1 * (1.0f / (float)BB) + tot2 * (1.0f / (float)(BB * GG));
    }
}

extern "C" void kernel_launch(void* const* d_in, const int* in_sizes, int n_in,
                              void* d_out, int out_size, void* d_ws, size_t ws_size,
                              hipStream_t stream) {
    const float* prob = (const float*)d_in[0];   // [B, H, W]
    const float* gt   = (const float*)d_in[1];   // [B, G, 2]
    const float* osz  = (const float*)d_in[2];   // [B, 2]
    float* out  = (float*)d_out;                 // [1]
    float* part = (float*)d_ws;                  // 1024*132 floats = 540 KB

    whd_main<<<BB * BPB, 256, 0, stream>>>(prob, gt, osz, part);
    whd_final<<<1, 1024, 0, stream>>>(part, out);
}

// Round 9
// 88.220 us; speedup vs baseline: 1.2705x; 1.0523x over previous
//
#include <hip/hip_runtime.h>
#include <math.h>

// Weighted Hausdorff Distance — B=8, H=W=256 (N=65536 pixels), G=128.
// Main kernel: 8-lane groups share a pixel-pair; each lane owns a 16-g chunk
// processed as 8 packed g-pairs (v2f -> v_pk_* f32 ops on gfx950).
// GT coords in SoA LDS (ysx/ysy), chunk stride 18 floats: 8 chunk bases on
// distinct even banks -> conflict-free aligned ds_read_b64 per g-pair.
// Partials layout: part[row][132], row = b*128 + blk (1024 rows).
//   cols 0..127 : per-g block sums of (wd+1e-6)^-9
//   col  128    : block sum of p*min_d
//   col  129    : block sum of p
// 1024*132*4 = 540,672 bytes of d_ws.

#define HH 256
#define WW 256
#define BB 8
#define GG 128
#define NPIX (HH * WW)
#define BPB 128                       // blocks per batch item
#define ROWW 132                      // padded row width
#define MAXD 362.03867196751236f      // sqrt(256^2 + 256^2)

typedef float v2f __attribute__((ext_vector_type(2)));

__device__ __forceinline__ float wave_sum(float v) {
    v += __shfl_xor(v, 1);  v += __shfl_xor(v, 2);  v += __shfl_xor(v, 4);
    v += __shfl_xor(v, 8);  v += __shfl_xor(v, 16); v += __shfl_xor(v, 32);
    return v;
}

__global__ __launch_bounds__(256, 4) void whd_main(const float* __restrict__ prob,
                                                   const float* __restrict__ gt,
                                                   const float* __restrict__ osz,
                                                   float* __restrict__ part) {
    const int bid  = blockIdx.x;
    const int b    = bid >> 7;            // / BPB
    const int blk  = bid & (BPB - 1);
    const int tid  = threadIdx.x;
    const int lane = tid & 63;
    const int wv   = tid >> 6;
    const int chunk = tid & 7;            // which 16-g chunk this lane owns
    const int pt    = tid >> 3;           // pixel-slot id, 0..31

    __shared__ float ysx[144];            // SoA, chunk c at offset c*18
    __shared__ float ysy[144];
    __shared__ float redS[4][137];
    __shared__ float2 redT[4];

    const float nh = osz[b * 2]     * (1.0f / (float)HH);
    const float nw = osz[b * 2 + 1] * (1.0f / (float)WW);

    if (tid < GG) {
        float gr = gt[(b * GG + tid) * 2];
        float gc = gt[(b * GG + tid) * 2 + 1];
        const int idx = (tid >> 4) * 18 + (tid & 15);
        ysx[idx] = gr * nh;
        ysy[idx] = gc * nw;
    }
    __syncthreads();

    const float* pb = prob + b * NPIX;

    v2f acc2[8];
#pragma unroll
    for (int j = 0; j < 8; j++) acc2[j] = (v2f)(0.0f);
    float t1acc = 0.0f, pacc = 0.0f;

    const int ysbase = chunk * 18;
    const int pix0   = blk * 512 + pt;

#pragma unroll 1
    for (int i = 0; i < 8; i++) {
        const int pixA = pix0 + i * 64;
        const int pixB = pixA + 32;
        const float pA = pb[pixA];
        const float pB = pb[pixB];
        const float xrA = (float)(pixA >> 8) * nh;
        const float xcA = (float)(pixA & 255) * nw;
        const float xrB = (float)(pixB >> 8) * nh;
        const float xcB = (float)(pixB & 255) * nw;
        // (1-p)*MAXD + 1e-6  (the wd + 1e-6 epsilon folded in)
        const float bA = (1.0f - pA) * MAXD + 1e-6f;
        const float bB = (1.0f - pB) * MAXD + 1e-6f;
        const v2f xrA2 = {xrA, xrA}, xcA2 = {xcA, xcA};
        const v2f xrB2 = {xrB, xrB}, xcB2 = {xcB, xcB};
        const v2f pA2  = {pA, pA},   bA2  = {bA, bA};
        const v2f pB2  = {pB, pB},   bB2  = {bB, bB};
        float mA = 1e30f, mB = 1e30f;

#pragma unroll
        for (int j2 = 0; j2 < 8; j2++) {
            const v2f yx = *(const v2f*)&ysx[ysbase + 2 * j2];
            const v2f yy = *(const v2f*)&ysy[ysbase + 2 * j2];
            // pixel A — packed over the g-pair
            v2f dxA = xrA2 - yx, dyA = xcA2 - yy;
            v2f sA  = dxA * dxA + dyA * dyA;          // pk_mul + pk_fma
            float dAlo = __builtin_amdgcn_sqrtf(sA.x);
            float dAhi = __builtin_amdgcn_sqrtf(sA.y);
            mA = fminf(mA, fminf(dAlo, dAhi));        // v_min3
            v2f dA2 = {dAlo, dAhi};
            v2f tA  = pA2 * dA2 + bA2;                // wd + 1e-6
            v2f uA  = tA * tA; uA = uA * uA; uA = uA * uA; uA = uA * tA; // t^9
            v2f rA  = {__builtin_amdgcn_rcpf(uA.x), __builtin_amdgcn_rcpf(uA.y)};
            // pixel B
            v2f dxB = xrB2 - yx, dyB = xcB2 - yy;
            v2f sB  = dxB * dxB + dyB * dyB;
            float dBlo = __builtin_amdgcn_sqrtf(sB.x);
            float dBhi = __builtin_amdgcn_sqrtf(sB.y);
            mB = fminf(mB, fminf(dBlo, dBhi));
            v2f dB2 = {dBlo, dBhi};
            v2f tB  = pB2 * dB2 + bB2;
            v2f uB  = tB * tB; uB = uB * uB; uB = uB * uB; uB = uB * tB;
            v2f rB  = {__builtin_amdgcn_rcpf(uB.x), __builtin_amdgcn_rcpf(uB.y)};
            acc2[j2] += (rA + rB);
        }
        // min over all 128 g: combine the 8 chunk-lanes sharing this pixel
        mA = fminf(mA, __shfl_xor(mA, 1)); mA = fminf(mA, __shfl_xor(mA, 2));
        mA = fminf(mA, __shfl_xor(mA, 4));
        mB = fminf(mB, __shfl_xor(mB, 1)); mB = fminf(mB, __shfl_xor(mB, 2));
        mB = fminf(mB, __shfl_xor(mB, 4));
        t1acc = fmaf(pA, mA, t1acc);
        t1acc = fmaf(pB, mB, t1acc);
        pacc += pA + pB;
    }

    // unpack packed accumulators to per-g scalars (g = chunk*16 + 2*j2 + half)
    float acc[16];
#pragma unroll
    for (int j2 = 0; j2 < 8; j2++) {
        acc[2 * j2]     = acc2[j2].x;
        acc[2 * j2 + 1] = acc2[j2].y;
    }

    // per-g sums: reduce across the 8 same-chunk lanes of this wave
#pragma unroll
    for (int j = 0; j < 16; j++) {
        float v = acc[j];
        v += __shfl_xor(v, 8);  v += __shfl_xor(v, 16); v += __shfl_xor(v, 32);
        acc[j] = v;
    }
    t1acc = wave_sum(t1acc);   // each pixel counted 8x (once per chunk lane)
    pacc  = wave_sum(pacc);

    if (lane < 8) {
#pragma unroll
        for (int j = 0; j < 16; j++) redS[wv][lane * 17 + j] = acc[j];
    }
    if (lane == 0) redT[wv] = make_float2(t1acc, pacc);
    __syncthreads();

    // coalesced partials write: row `bid`, 128 consecutive floats + (t1,p)
    if (tid < GG) {
        const int idx = (tid >> 4) * 17 + (tid & 15);   // g == tid
        part[bid * ROWW + tid] =
            redS[0][idx] + redS[1][idx] + redS[2][idx] + redS[3][idx];
    } else if (tid == GG) {
        float t1 = redT[0].x + redT[1].x + redT[2].x + redT[3].x;
        float pp = redT[0].y + redT[1].y + redT[2].y + redT[3].y;
        part[bid * ROWW + 128] = t1 * 0.125f;   // undo 8x pixel multiplicity
        part[bid * ROWW + 129] = pp * 0.125f;
    }
}

__global__ __launch_bounds__(1024) void whd_final(const float* __restrict__ part,
                                                  float* __restrict__ out) {
    const int tid  = threadIdx.x;       // 0..1023, one (b,g) pair per thread
    const int lane = tid & 63;
    const int wv   = tid >> 6;          // 0..15
    const int b    = tid >> 7;
    const int g    = tid & 127;

    // term2: sum over this b's 128 blocks; lanes read consecutive g -> coalesced
    const float* base = part + (b * BPB) * ROWW + g;
    float s = 0.0f;
#pragma unroll 8
    for (int k = 0; k < BPB; k++) s += base[k * ROWW];
    float mean = s * (1.0f / (float)NPIX);
    float a2 = powf(mean, -0.111111111111111111f);   // 1 / P_EXP

    // term1 partials: thread tid reads row tid's (t1, p)
    const float2 tp = *(const float2*)(part + tid * ROWW + 128);

    float wa = wave_sum(a2);
    float wt = wave_sum(tp.x);   // rows of one b span exactly 2 waves
    float wp = wave_sum(tp.y);

    __shared__ float sA[16], sT[16], sP[16];
    if (lane == 0) { sA[wv] = wa; sT[wv] = wt; sP[wv] = wp; }
    __syncthreads();

    if (tid == 0) {
        float tot2 = 0.0f;
#pragma unroll
        for (int w = 0; w < 16; w++) tot2 += sA[w];
        float tot1 = 0.0f;
#pragma unroll
        for (int bb = 0; bb < BB; bb++) {
            float tb = sT[2 * bb] + sT[2 * bb + 1];
            float pb = sP[2 * bb] + sP[2 * bb + 1];
            tot1 += tb / (pb + 1e-6f);
        }
        out[0] = tot1 * (1.0f / (float)BB) + tot2 * (1.0f / (float)(BB * GG));
    }
}

extern "C" void kernel_launch(void* const* d_in, const int* in_sizes, int n_in,
                              void* d_out, int out_size, void* d_ws, size_t ws_size,
                              hipStream_t stream) {
    const float* prob = (const float*)d_in[0];   // [B, H, W]
    const float* gt   = (const float*)d_in[1];   // [B, G, 2]
    const float* osz  = (const float*)d_in[2];   // [B, 2]
    float* out  = (float*)d_out;                 // [1]
    float* part = (float*)d_ws;                  // 1024*132 floats = 540 KB

    whd_main<<<BB * BPB, 256, 0, stream>>>(prob, gt, osz, part);
    whd_final<<<1, 1024, 0, stream>>>(part, out);
}

// Round 10
// 84.508 us; speedup vs baseline: 1.3263x; 1.0439x over previous
//
#include <hip/hip_runtime.h>
#include <math.h>

// Weighted Hausdorff Distance — B=8, H=W=256 (N=65536 pixels), G=128.
// Main kernel: 8-lane groups share a pixel-pair; each lane owns a 16-g chunk
// processed as 8 packed g-pairs (v2f -> v_pk_* f32 ops on gfx950).
// GT coords in SoA LDS (ysx/ysy), chunk stride 18 floats: conflict-free
// aligned ds_read_b64 per g-pair.
// Partials layout: part[row][132], row = b*128 + blk (1024 rows).
//   cols 0..127 : per-g block sums of (wd+1e-6)^-9
//   col  128    : block sum of p*min_d
//   col  129    : block sum of p
// Results area at float offset RES_OFF: 2 floats per b (a1_b, t2sum_b),
// completion counter (uint) at RES_OFF+16. Counter zeroed by whd_main
// block 0 each call (kernel-boundary ordering), finalize uses device-scope
// atomicAdd + threadfence for the last-block combine.

#define HH 256
#define WW 256
#define BB 8
#define GG 128
#define NPIX (HH * WW)
#define BPB 128                       // blocks per batch item
#define ROWW 132                      // padded row width
#define RES_OFF (1024 * ROWW)
#define MAXD 362.03867196751236f      // sqrt(256^2 + 256^2)

typedef float v2f __attribute__((ext_vector_type(2)));

__device__ __forceinline__ float wave_sum(float v) {
    v += __shfl_xor(v, 1);  v += __shfl_xor(v, 2);  v += __shfl_xor(v, 4);
    v += __shfl_xor(v, 8);  v += __shfl_xor(v, 16); v += __shfl_xor(v, 32);
    return v;
}

__global__ __launch_bounds__(256, 4) void whd_main(const float* __restrict__ prob,
                                                   const float* __restrict__ gt,
                                                   const float* __restrict__ osz,
                                                   float* __restrict__ part) {
    const int bid  = blockIdx.x;
    const int b    = bid >> 7;            // / BPB
    const int blk  = bid & (BPB - 1);
    const int tid  = threadIdx.x;
    const int lane = tid & 63;
    const int wv   = tid >> 6;
    const int chunk = tid & 7;            // which 16-g chunk this lane owns
    const int pt    = tid >> 3;           // pixel-slot id, 0..31

    __shared__ float ysx[144];            // SoA, chunk c at offset c*18
    __shared__ float ysy[144];
    __shared__ float redS[4][137];
    __shared__ float2 redT[4];

    // re-zero the finalize completion counter every call (ws is 0xAA-poisoned)
    if (bid == 0 && tid == 129) {
        *(unsigned int*)(part + RES_OFF + 16) = 0u;
    }

    const float nh = osz[b * 2]     * (1.0f / (float)HH);
    const float nw = osz[b * 2 + 1] * (1.0f / (float)WW);

    if (tid < GG) {
        float gr = gt[(b * GG + tid) * 2];
        float gc = gt[(b * GG + tid) * 2 + 1];
        const int idx = (tid >> 4) * 18 + (tid & 15);
        ysx[idx] = gr * nh;
        ysy[idx] = gc * nw;
    }
    __syncthreads();

    const float* pb = prob + b * NPIX;

    v2f acc2[8];
#pragma unroll
    for (int j = 0; j < 8; j++) acc2[j] = (v2f)(0.0f);
    float t1acc = 0.0f, pacc = 0.0f;

    const int ysbase = chunk * 18;
    const int pix0   = blk * 512 + pt;

#pragma unroll 1
    for (int i = 0; i < 8; i++) {
        const int pixA = pix0 + i * 64;
        const int pixB = pixA + 32;
        const float pA = pb[pixA];
        const float pB = pb[pixB];
        const float xrA = (float)(pixA >> 8) * nh;
        const float xcA = (float)(pixA & 255) * nw;
        const float xrB = (float)(pixB >> 8) * nh;
        const float xcB = (float)(pixB & 255) * nw;
        // (1-p)*MAXD + 1e-6  (the wd + 1e-6 epsilon folded in)
        const float bA = (1.0f - pA) * MAXD + 1e-6f;
        const float bB = (1.0f - pB) * MAXD + 1e-6f;
        const v2f xrA2 = {xrA, xrA}, xcA2 = {xcA, xcA};
        const v2f xrB2 = {xrB, xrB}, xcB2 = {xcB, xcB};
        const v2f pA2  = {pA, pA},   bA2  = {bA, bA};
        const v2f pB2  = {pB, pB},   bB2  = {bB, bB};
        float mA = 1e30f, mB = 1e30f;

#pragma unroll
        for (int j2 = 0; j2 < 8; j2++) {
            const v2f yx = *(const v2f*)&ysx[ysbase + 2 * j2];
            const v2f yy = *(const v2f*)&ysy[ysbase + 2 * j2];
            // pixel A — packed over the g-pair
            v2f dxA = xrA2 - yx, dyA = xcA2 - yy;
            v2f sA  = dxA * dxA + dyA * dyA;          // pk_mul + pk_fma
            float dAlo = __builtin_amdgcn_sqrtf(sA.x);
            float dAhi = __builtin_amdgcn_sqrtf(sA.y);
            mA = fminf(mA, fminf(dAlo, dAhi));        // v_min3
            v2f dA2 = {dAlo, dAhi};
            v2f tA  = pA2 * dA2 + bA2;                // wd + 1e-6
            v2f uA  = tA * tA; uA = uA * uA; uA = uA * uA; uA = uA * tA; // t^9
            v2f rA  = {__builtin_amdgcn_rcpf(uA.x), __builtin_amdgcn_rcpf(uA.y)};
            // pixel B
            v2f dxB = xrB2 - yx, dyB = xcB2 - yy;
            v2f sB  = dxB * dxB + dyB * dyB;
            float dBlo = __builtin_amdgcn_sqrtf(sB.x);
            float dBhi = __builtin_amdgcn_sqrtf(sB.y);
            mB = fminf(mB, fminf(dBlo, dBhi));
            v2f dB2 = {dBlo, dBhi};
            v2f tB  = pB2 * dB2 + bB2;
            v2f uB  = tB * tB; uB = uB * uB; uB = uB * uB; uB = uB * tB;
            v2f rB  = {__builtin_amdgcn_rcpf(uB.x), __builtin_amdgcn_rcpf(uB.y)};
            acc2[j2] += (rA + rB);
        }
        // min over all 128 g: combine the 8 chunk-lanes sharing this pixel
        mA = fminf(mA, __shfl_xor(mA, 1)); mA = fminf(mA, __shfl_xor(mA, 2));
        mA = fminf(mA, __shfl_xor(mA, 4));
        mB = fminf(mB, __shfl_xor(mB, 1)); mB = fminf(mB, __shfl_xor(mB, 2));
        mB = fminf(mB, __shfl_xor(mB, 4));
        t1acc = fmaf(pA, mA, t1acc);
        t1acc = fmaf(pB, mB, t1acc);
        pacc += pA + pB;
    }

    // unpack packed accumulators to per-g scalars (g = chunk*16 + 2*j2 + half)
    float acc[16];
#pragma unroll
    for (int j2 = 0; j2 < 8; j2++) {
        acc[2 * j2]     = acc2[j2].x;
        acc[2 * j2 + 1] = acc2[j2].y;
    }

    // per-g sums: reduce across the 8 same-chunk lanes of this wave
#pragma unroll
    for (int j = 0; j < 16; j++) {
        float v = acc[j];
        v += __shfl_xor(v, 8);  v += __shfl_xor(v, 16); v += __shfl_xor(v, 32);
        acc[j] = v;
    }
    t1acc = wave_sum(t1acc);   // each pixel counted 8x (once per chunk lane)
    pacc  = wave_sum(pacc);

    if (lane < 8) {
#pragma unroll
        for (int j = 0; j < 16; j++) redS[wv][lane * 17 + j] = acc[j];
    }
    if (lane == 0) redT[wv] = make_float2(t1acc, pacc);
    __syncthreads();

    // coalesced partials write: row `bid`, 128 consecutive floats + (t1,p)
    if (tid < GG) {
        const int idx = (tid >> 4) * 17 + (tid & 15);   // g == tid
        part[bid * ROWW + tid] =
            redS[0][idx] + redS[1][idx] + redS[2][idx] + redS[3][idx];
    } else if (tid == GG) {
        float t1 = redT[0].x + redT[1].x + redT[2].x + redT[3].x;
        float pp = redT[0].y + redT[1].y + redT[2].y + redT[3].y;
        part[bid * ROWW + 128] = t1 * 0.125f;   // undo 8x pixel multiplicity
        part[bid * ROWW + 129] = pp * 0.125f;
    }
}

__global__ __launch_bounds__(256) void whd_final(float* __restrict__ part,
                                                 float* __restrict__ out) {
    const int bb   = blockIdx.x;        // 0..7, one block per batch item
    const int tid  = threadIdx.x;
    const int g    = tid & 127;
    const int half = tid >> 7;          // 0: rows 0..63, 1: rows 64..127

    // term2 partial: sum this b's rows (split in 2 halves); coalesced over g
    const float* base = part + (bb * BPB + half * 64) * ROWW + g;
    float s = 0.0f;
#pragma unroll 8
    for (int k = 0; k < 64; k++) s += base[k * ROWW];

    __shared__ float sh[128];
    if (half == 1) sh[g] = s;
    __syncthreads();

    float a2 = 0.0f;
    float2 tp = make_float2(0.0f, 0.0f);
    if (half == 0) {
        float tot  = s + sh[g];
        float mean = tot * (1.0f / (float)NPIX);
        a2 = powf(mean, -0.111111111111111111f);   // 1 / P_EXP
        // term1 partials: thread g reads row (bb*BPB+g)'s (t1, p)
        tp = *(const float2*)(part + (bb * BPB + g) * ROWW + 128);
    }

    float wa = wave_sum(a2);
    float wt = wave_sum(tp.x);
    float wp = wave_sum(tp.y);

    __shared__ float rA[4], rT[4], rP[4];
    if ((tid & 63) == 0) { rA[tid >> 6] = wa; rT[tid >> 6] = wt; rP[tid >> 6] = wp; }
    __syncthreads();

    if (tid == 0) {
        float t2b = rA[0] + rA[1] + rA[2] + rA[3];   // waves 2,3 contribute 0
        float t1b = rT[0] + rT[1] + rT[2] + rT[3];
        float ppb = rP[0] + rP[1] + rP[2] + rP[3];
        part[RES_OFF + 2 * bb]     = t1b / (ppb + 1e-6f);
        part[RES_OFF + 2 * bb + 1] = t2b;
        __threadfence();
        unsigned int old = atomicAdd((unsigned int*)(part + RES_OFF + 16), 1u);
        if (old == BB - 1) {
            __threadfence();
            float s1 = 0.0f, s2 = 0.0f;
#pragma unroll
            for (int q = 0; q < BB; q++) {
                s1 += part[RES_OFF + 2 * q];
                s2 += part[RES_OFF + 2 * q + 1];
            }
            out[0] = s1 * (1.0f / (float)BB) + s2 * (1.0f / (float)(BB * GG));
        }
    }
}

extern "C" void kernel_launch(void* const* d_in, const int* in_sizes, int n_in,
                              void* d_out, int out_size, void* d_ws, size_t ws_size,
                              hipStream_t stream) {
    const float* prob = (const float*)d_in[0];   // [B, H, W]
    const float* gt   = (const float*)d_in[1];   // [B, G, 2]
    const float* osz  = (const float*)d_in[2];   // [B, 2]
    float* out  = (float*)d_out;                 // [1]
    float* part = (float*)d_ws;                  // partials + results + counter

    whd_main<<<BB * BPB, 256, 0, stream>>>(prob, gt, osz, part);
    whd_final<<<BB, 256, 0, stream>>>(part, out);
}